// Round 4
// baseline (2722.368 us; speedup 1.0000x reference)
//
#include <hip/hip_runtime.h>
#include <math.h>

#define B_SZ 64
#define T_IN 80
#define H_SZ 256
#define V_SZ 6144
#define L_DEC 30
#define SYMBASE (B_SZ * L_DEC * V_SZ)
#define NDB 64             // decoder blocks
#define SLOT_STRIDE 32     // barrier slot padding (ints, 128B)

typedef unsigned long long u64;

__device__ __forceinline__ float sigf(float x) { return 1.f / (1.f + expf(-x)); }

__device__ __forceinline__ void fma4(float4& a, float s, float4 w) {
    a.x = fmaf(s, w.x, a.x); a.y = fmaf(s, w.y, a.y);
    a.z = fmaf(s, w.z, a.z); a.w = fmaf(s, w.w, a.w);
}
__device__ __forceinline__ float4 add4(float4 a, float4 b) {
    return make_float4(a.x + b.x, a.y + b.y, a.z + b.z, a.w + b.w);
}
// monotone float->uint pack, first-index tie-break in low bits
__device__ __forceinline__ u64 packmax(float v, int idx) {
    unsigned u = __float_as_uint(v);
    u = (u & 0x80000000u) ? ~u : (u | 0x80000000u);
    return ((u64)u << 32) | (unsigned)(0x7FFFFFFF - idx);
}
// LDS float4-slot swizzle for h[64][256]: slot s of batch b -> s ^ (b&7)
__device__ __forceinline__ int hslot(int b, int s) { return (b << 6) + (s ^ (b & 7)); }

// ---------------- bias sums ----------------
__global__ void biasum(const float* a1, const float* b1, const float* a2, const float* b2,
                       float* o1, float* o2) {
    int i = blockIdx.x * 256 + threadIdx.x;
    if (i < 1024) { o1[i] = a1[i] + b1[i]; o2[i] = a2[i] + b2[i]; }
}

// ---------------- init: zero barrier slots + go ----------------
__global__ void init0(int* slots) {
    int i = blockIdx.x * 256 + threadIdx.x;      // 9*256 = 2304 >= 2080
    if (i < NDB * SLOT_STRIDE + SLOT_STRIDE) slots[i] = 0;
}

// ---------------- pack [1024][256] -> gate-float4 [256 k][256 u] ----------------
__global__ __launch_bounds__(256) void packW(const float* __restrict__ W,
                                             float4* __restrict__ Wq) {
    int idx = blockIdx.x * 256 + threadIdx.x;    // 65536
    int u = idx & 255, k = idx >> 8;
    Wq[k * 256 + u] = make_float4(W[(size_t)u * 256 + k],
                                  W[(size_t)(u + 256) * 256 + k],
                                  W[(size_t)(u + 512) * 256 + k],
                                  W[(size_t)(u + 768) * 256 + k]);
}

// ---------------- tiled fp32 GEMM: C = A[M][K] * W[N][K]^T + bias, gate-permuted cols ----
template <int PERM>
__global__ __launch_bounds__(256) void gemm_rr(const float* __restrict__ A,
                                               const float* __restrict__ W,
                                               const float* __restrict__ bias,
                                               float* __restrict__ C,
                                               int M, int N, int K) {
    __shared__ __align__(16) float As[16][68];
    __shared__ __align__(16) float Bs[16][132];
    const int tid = threadIdx.x;
    const int tx = tid & 15, ty = tid >> 4;
    const int m0 = blockIdx.y * 64, n0 = blockIdx.x * 128;
    const int a_m = tid >> 2, a_k = (tid & 3) * 4;
    const int b_n = tid >> 1, b_k = (tid & 1) * 8;

    float acc[4][8];
#pragma unroll
    for (int r = 0; r < 4; ++r)
#pragma unroll
        for (int c = 0; c < 8; ++c) acc[r][c] = 0.f;

    for (int k0 = 0; k0 < K; k0 += 16) {
        float4 av  = *(const float4*)(A + (size_t)(m0 + a_m) * K + k0 + a_k);
        float4 bv0 = *(const float4*)(W + (size_t)(n0 + b_n) * K + k0 + b_k);
        float4 bv1 = *(const float4*)(W + (size_t)(n0 + b_n) * K + k0 + b_k + 4);
        __syncthreads();
        As[a_k + 0][a_m] = av.x; As[a_k + 1][a_m] = av.y;
        As[a_k + 2][a_m] = av.z; As[a_k + 3][a_m] = av.w;
        Bs[b_k + 0][b_n] = bv0.x; Bs[b_k + 1][b_n] = bv0.y;
        Bs[b_k + 2][b_n] = bv0.z; Bs[b_k + 3][b_n] = bv0.w;
        Bs[b_k + 4][b_n] = bv1.x; Bs[b_k + 5][b_n] = bv1.y;
        Bs[b_k + 6][b_n] = bv1.z; Bs[b_k + 7][b_n] = bv1.w;
        __syncthreads();
#pragma unroll
        for (int kk = 0; kk < 16; ++kk) {
            float4 a0 = *(const float4*)&As[kk][ty * 4];
            float4 b0 = *(const float4*)&Bs[kk][tx * 8];
            float4 b1 = *(const float4*)&Bs[kk][tx * 8 + 4];
            float ar[4] = {a0.x, a0.y, a0.z, a0.w};
            float br[8] = {b0.x, b0.y, b0.z, b0.w, b1.x, b1.y, b1.z, b1.w};
#pragma unroll
            for (int r = 0; r < 4; ++r)
#pragma unroll
                for (int c = 0; c < 8; ++c)
                    acc[r][c] = fmaf(ar[r], br[c], acc[r][c]);
        }
    }
#pragma unroll
    for (int r = 0; r < 4; ++r) {
        float* Crow = C + (size_t)(m0 + ty * 4 + r) * N;
#pragma unroll
        for (int c = 0; c < 8; ++c) {
            int j = n0 + tx * 8 + c;
            int jp = PERM ? ((j & 255) * 4 + (j >> 8)) : j;
            Crow[jp] = acc[r][c] + bias[j];
        }
    }
}

// ---------------- step-0 outputs: dec_o0 broadcast + SOS symbols ----------------
__global__ __launch_bounds__(256) void dec0(const float* __restrict__ embed,
                                            const float* __restrict__ Wout,
                                            const float* __restrict__ bout,
                                            float* __restrict__ out) {
    __shared__ float es[256];
    int tid = threadIdx.x;
    int v = blockIdx.x * 256 + tid;
    es[tid] = embed[256 + tid];  // row SOS=1
    __syncthreads();
    float a = 0.f, a2 = 0.f;
    const float* wr = Wout + (size_t)v * 256;
    for (int k = 0; k < 256; k += 8) {
        float4 w0 = *(const float4*)(wr + k);
        float4 w1 = *(const float4*)(wr + k + 4);
        a  = fmaf(es[k+0],w0.x,fmaf(es[k+1],w0.y,fmaf(es[k+2],w0.z,fmaf(es[k+3],w0.w,a))));
        a2 = fmaf(es[k+4],w1.x,fmaf(es[k+5],w1.y,fmaf(es[k+6],w1.z,fmaf(es[k+7],w1.w,a2))));
    }
    float lg = a + a2 + bout[v];
    for (int b = 0; b < B_SZ; ++b) out[(size_t)b * L_DEC * V_SZ + v] = lg;
    if (blockIdx.x == 0 && tid < B_SZ) out[SYMBASE + tid * L_DEC] = 1.0f;
}

// ---------------- encoder: one block per batch element, zero sync ----------------
__global__ __launch_bounds__(1024) void enc_fused(const float4* __restrict__ Wq1,  // [256k][256u]
                                                  const float4* __restrict__ Xq,   // [5120][256] f4
                                                  float* __restrict__ hb0,         // = hR[0]
                                                  float* __restrict__ cfin) {
    __shared__ float hs[H_SZ];
    __shared__ float cs[H_SZ];
    __shared__ __align__(16) float4 pp[4][H_SZ];
    const int tid = threadIdx.x;
    const int b = blockIdx.x;
    const int u = tid & 255;
    const int q = tid >> 8;              // k-quarter 0..3
    if (tid < 256) { hs[tid] = 0.f; cs[tid] = 0.f; }
    __syncthreads();

    for (int t = 0; t < T_IN; ++t) {
        float4 acc = {0.f, 0.f, 0.f, 0.f};
        const float4* wp = Wq1 + (size_t)(q * 64) * 256 + u;
        const float4* hp = (const float4*)hs + q * 16;
#pragma unroll 4
        for (int i = 0; i < 16; ++i) {
            float4 hv = hp[i];
            fma4(acc, hv.x, wp[0]);
            fma4(acc, hv.y, wp[256]);
            fma4(acc, hv.z, wp[512]);
            fma4(acc, hv.w, wp[768]);
            wp += 1024;
        }
        pp[q][u] = acc;
        __syncthreads();
        if (tid < 256) {
            float4 g = add4(add4(pp[0][tid], pp[1][tid]), add4(pp[2][tid], pp[3][tid]));
            float4 xg = Xq[(size_t)(b * T_IN + t) * 256 + tid];
            float gi = g.x + xg.x, gf = g.y + xg.y, gg = g.z + xg.z, go = g.w + xg.w;
            float cn = sigf(gf) * cs[tid] + sigf(gi) * tanhf(gg);
            float hn = sigf(go) * tanhf(cn);
            cs[tid] = cn;
            hs[tid] = hn;
            if (t == T_IN - 1) {
                hb0[b * 256 + tid] = hn;
                cfin[b * 256 + tid] = cn;
            }
        }
        __syncthreads();
    }
}

// ---------------- hub barrier: arrivals -> block0 polls -> one go word ----------
__device__ __forceinline__ void barX(int* slots, int* go, int x, int phase, int tid) {
    __syncthreads();   // drains vmcnt before s_barrier -> prior sc1 data stores done
    if (tid == 0)
        __hip_atomic_store(&slots[x * SLOT_STRIDE], phase,
                           __ATOMIC_RELAXED, __HIP_MEMORY_SCOPE_AGENT);
    if (x == 0) {
        if (tid < 64) {
            while (__hip_atomic_load(&slots[tid * SLOT_STRIDE],
                                     __ATOMIC_RELAXED, __HIP_MEMORY_SCOPE_AGENT) < phase)
                __builtin_amdgcn_s_sleep(2);
        }
        if (tid == 0)
            __hip_atomic_store(go, phase, __ATOMIC_RELAXED, __HIP_MEMORY_SCOPE_AGENT);
    } else if (tid == 0) {
        while (__hip_atomic_load(go, __ATOMIC_RELAXED, __HIP_MEMORY_SCOPE_AGENT) < phase)
            __builtin_amdgcn_s_sleep(2);
    }
    asm volatile("" ::: "memory");   // no load hoisting above the wait
    __syncthreads();
}

// ---------------- decoder: 64 blocks x 512 threads ----------------
// Block x owns LSTM2 units [4x,4x+4) + logit cols [96x, 96x+96).
__global__ __launch_bounds__(512) void dec_fused(
    const float4* __restrict__ Wq2,    // Whh2 packed [256k][256u]
    const float4* __restrict__ Wxq2,   // W_ih2 packed [256k][256u]
    const float4* __restrict__ embed4, // [V][64] f4
    const float* __restrict__ Wout,    // [6144][256]
    const float* __restrict__ bout,
    const float* __restrict__ bs2,     // b_ih2+b_hh2 [1024]
    float* __restrict__ hR,            // [30][16384], hR[0] = h_enc
    const float* __restrict__ cfin,
    u64* __restrict__ parts,           // [29][64 b][64 x]
    int* __restrict__ slots, int* __restrict__ go,
    float* __restrict__ out) {
    __shared__ __align__(16) float4 hs4[4096];   // swizzled h[64][256]
    __shared__ __align__(16) float4 gp[2][4][64];
    __shared__ u64 pm[8][64];
    __shared__ float cs[4][64];
    __shared__ int ssym[64];
    const int tid = threadIdx.x;
    const int x = blockIdx.x;
    const int b = tid & 63;
    const int w = tid >> 6;

    {   // init: stage h_enc (plain loads: kernel-boundary coherence), c, sym
        const float4* hf4 = (const float4*)hR;
#pragma unroll
        for (int i = tid; i < 4096; i += 512) {
            int bb = i >> 6, s = i & 63;
            hs4[hslot(bb, s)] = hf4[i];
        }
        if (tid < 256) cs[tid >> 6][tid & 63] = cfin[(tid & 63) * 256 + x * 4 + (tid >> 6)];
        if (tid < 64) ssym[tid] = 1;
    }
    __syncthreads();

    int phase = 0;
    for (int l = 0; l < L_DEC - 1; ++l) {
        // ---- LSTM2 gates: h-part + x-part (embed[sym] @ W_ih2^T) ----
        {
            const int uu = w & 3, ks = w >> 2;
            const int u  = __builtin_amdgcn_readfirstlane(x * 4 + uu);
            const int k0 = __builtin_amdgcn_readfirstlane(ks * 128);
            const int row = ssym[b];
            float4 acc = {0.f, 0.f, 0.f, 0.f};
            const float4* wp  = Wq2  + (size_t)k0 * 256 + u;
            const float4* wxp = Wxq2 + (size_t)k0 * 256 + u;
            const float4* ep  = embed4 + (size_t)row * 64 + (k0 >> 2);
#pragma unroll 8
            for (int i = 0; i < 32; ++i) {
                float4 hv = hs4[(b << 6) + (((k0 >> 2) + i) ^ (b & 7))];
                float4 ev = ep[i];
                fma4(acc, hv.x, wp[0]);   fma4(acc, hv.y, wp[256]);
                fma4(acc, hv.z, wp[512]); fma4(acc, hv.w, wp[768]);
                fma4(acc, ev.x, wxp[0]);  fma4(acc, ev.y, wxp[256]);
                fma4(acc, ev.z, wxp[512]); fma4(acc, ev.w, wxp[768]);
                wp += 1024; wxp += 1024;
            }
            gp[ks][uu][b] = acc;
        }
        __syncthreads();
        float* hnext = hR + (size_t)(l + 1) * 16384;
        if (tid < 256) {
            const int uu = tid >> 6, bb = tid & 63;
            const int u = x * 4 + uu;
            float4 g = add4(gp[0][uu][bb], gp[1][uu][bb]);
            float gi  = g.x + bs2[u];
            float gf  = g.y + bs2[u + 256];
            float gg  = g.z + bs2[u + 512];
            float go_ = g.w + bs2[u + 768];
            float cn = sigf(gf) * cs[uu][bb] + sigf(gi) * tanhf(gg);
            cs[uu][bb] = cn;
            float hn = sigf(go_) * tanhf(cn);
            __hip_atomic_store(&hnext[bb * 256 + u], hn,
                               __ATOMIC_RELAXED, __HIP_MEMORY_SCOPE_AGENT);
        }
        ++phase; barX(slots, go, x, phase, tid);     // barrier A: h' in L3

        // ---- stage h_{l+1}: plain coalesced loads (fresh addresses this call) ----
        {
            const float4* hf4 = (const float4*)hnext;
#pragma unroll
            for (int i = tid; i < 4096; i += 512) {
                int bb = i >> 6, s = i & 63;
                hs4[hslot(bb, s)] = hf4[i];
            }
        }
        __syncthreads();

        // ---- logits: 12 cols per wave, lane = batch; wave-uniform W rows ----
        {
            const int v0 = __builtin_amdgcn_readfirstlane(x * 96 + w * 12);
            float acc[12];
#pragma unroll
            for (int c = 0; c < 12; ++c) acc[c] = 0.f;
            const float* w0 = Wout + (size_t)v0 * 256;
#pragma unroll 2
            for (int k4 = 0; k4 < 64; ++k4) {
                float4 hv = hs4[(b << 6) + (k4 ^ (b & 7))];
#pragma unroll
                for (int c = 0; c < 12; ++c) {
                    float4 ww = *(const float4*)(w0 + (size_t)c * 256 + k4 * 4);
                    acc[c] = fmaf(hv.x, ww.x, fmaf(hv.y, ww.y,
                             fmaf(hv.z, ww.z, fmaf(hv.w, ww.w, acc[c]))));
                }
            }
            u64 best = 0ull;
            float* orow = out + (size_t)(b * L_DEC + l + 1) * V_SZ + v0;
#pragma unroll
            for (int c = 0; c < 12; ++c) {
                float lg = acc[c] + bout[v0 + c];
                orow[c] = lg;
                u64 p = packmax(lg, v0 + c);
                if (p > best) best = p;
            }
            pm[w][b] = best;
        }
        __syncthreads();
        u64* pstep = parts + (size_t)l * 4096;
        if (tid < 64) {
            u64 m = pm[0][tid];
#pragma unroll
            for (int j = 1; j < 8; ++j) if (pm[j][tid] > m) m = pm[j][tid];
            __hip_atomic_store(&pstep[tid * 64 + x], m,
                               __ATOMIC_RELAXED, __HIP_MEMORY_SCOPE_AGENT);
        }
        ++phase; barX(slots, go, x, phase, tid);     // barrier B: partials in L3

        // ---- global argmax (redundant per block; plain loads, rotating buffer) ----
        {
            const u64* pr = pstep + b * 64 + (w << 3);
            u64 m = 0ull;
#pragma unroll
            for (int j = 0; j < 8; ++j) { u64 p = pr[j]; if (p > m) m = p; }
            pm[w][b] = m;
        }
        __syncthreads();
        if (tid < 64) {
            u64 m = pm[0][tid];
#pragma unroll
            for (int j = 1; j < 8; ++j) if (pm[j][tid] > m) m = pm[j][tid];
            int idx = (int)(0x7FFFFFFFu - (unsigned)(m & 0xFFFFFFFFu));
            ssym[tid] = idx;
            if (x == tid) out[SYMBASE + tid * L_DEC + l + 1] = (float)idx;
        }
        __syncthreads();
    }
}

extern "C" void kernel_launch(void* const* d_in, const int* in_sizes, int n_in,
                              void* d_out, int out_size, void* d_ws, size_t ws_size,
                              hipStream_t stream) {
    const float* input = (const float*)d_in[0];
    // d_in[1] target_lengths: all == L_DEC, unused
    const float* embed = (const float*)d_in[2];
    const float* W_out = (const float*)d_in[3];
    const float* b_out = (const float*)d_in[4];
    const float* W_ih1 = (const float*)d_in[5];
    const float* W_hh1 = (const float*)d_in[6];
    const float* b_ih1 = (const float*)d_in[7];
    const float* b_hh1 = (const float*)d_in[8];
    const float* W_ih2 = (const float*)d_in[9];
    const float* W_hh2 = (const float*)d_in[10];
    const float* b_ih2 = (const float*)d_in[11];
    const float* b_hh2 = (const float*)d_in[12];
    float* out = (float*)d_out;

    float* ws = (float*)d_ws;
    float* X1q  = ws; ws += 5120 * 1024;       // gate-packed X1
    float* Wq1  = ws; ws += 256 * 1024;        // Whh1 packed
    float* Wq2  = ws; ws += 256 * 1024;        // Whh2 packed
    float* Wxq2 = ws; ws += 256 * 1024;        // W_ih2 packed
    float* hR   = ws; ws += L_DEC * 16384;     // rotating h buffers, hR[0]=h_enc
    float* cfin = ws; ws += 16384;
    float* bs1  = ws; ws += 1024;
    float* bs2  = ws; ws += 1024;
    u64*  parts = (u64*)ws; ws += 2 * 29 * 4096;        // rotating argmax partials
    int*  slots = (int*)ws; ws += NDB * SLOT_STRIDE + SLOT_STRIDE;
    int*  go    = slots + NDB * SLOT_STRIDE;
    if (ws_size < (size_t)((float*)ws - (float*)d_ws) * 4) return;

    biasum<<<4, 256, 0, stream>>>(b_ih1, b_hh1, b_ih2, b_hh2, bs1, bs2);
    init0<<<9, 256, 0, stream>>>(slots);
    packW<<<256, 256, 0, stream>>>(W_hh1, (float4*)Wq1);
    packW<<<256, 256, 0, stream>>>(W_hh2, (float4*)Wq2);
    packW<<<256, 256, 0, stream>>>(W_ih2, (float4*)Wxq2);
    // X1q = gatepack(input @ W_ih1^T + (b_ih1+b_hh1)) : [5120 x 1024], K=4096
    gemm_rr<1><<<dim3(8, 80), 256, 0, stream>>>(input, W_ih1, bs1, X1q, 5120, 1024, 4096);
    dec0<<<24, 256, 0, stream>>>(embed, W_out, b_out, out);
    enc_fused<<<64, 1024, 0, stream>>>((const float4*)Wq1, (const float4*)X1q, hR, cfin);
    dec_fused<<<NDB, 512, 0, stream>>>((const float4*)Wq2, (const float4*)Wxq2,
                                       (const float4*)embed, W_out, b_out, bs2,
                                       hR, cfin, parts, slots, go, out);
}